// Round 2
// baseline (6774.278 us; speedup 1.0000x reference)
//
#include <hip/hip_runtime.h>
#include <hip/hip_bf16.h>

typedef __hip_bfloat16 bf16;

#define DEV __device__ __forceinline__

template<class T> struct Cvt;
template<> struct Cvt<float> {
  DEV static float to(float v) { return v; }
  DEV static float from(float v) { return v; }
};
template<> struct Cvt<bf16> {
  DEV static float to(bf16 v) { return __bfloat162float(v); }
  DEV static bf16 from(float v) { return __float2bfloat16(v); }
};

DEV float sigmoid_f(float x) { return 1.f / (1.f + __expf(-x)); }
// 1 - 2/(e^{2x}+1): no NaN at +/-inf, ~1e-7 abs err
DEV float tanh_f(float x) { return 1.f - 2.f / (__expf(2.f * x) + 1.f); }

// ---------------------------------------------------------------------------
// Problem constants: N=4096 graphs, K=8 nodes, n_in=14, H=128, k=3 iterations
// ALL float inputs are fp32 (setup_inputs uses default fp32); output fp32.
// Edge GRU:  kdim = 284 (x, pad 288) + 128 (h)  -> KXC=18, KHC=8 (chunks of 16)
// Node GRU:  kdim = 142 (x, pad 160) + 128 (h)  -> KXC=10, KHC=8
// Global GRU:kdim = 256 (x)          + 128 (h=0)-> KXC=16, KHC=8
// Interleaved weight layout WT[kc][cg][gate], gate = (r, z, i_n, h_n)
// ---------------------------------------------------------------------------

__global__ __launch_bounds__(256) void prep_gruWT(
    const float* __restrict__ Wih, const float* __restrict__ Whh,
    float* __restrict__ WT, int KXW, int KXP, int KTOT)
{
  const int idx = blockIdx.x * 256 + threadIdx.x;
  if (idx >= KTOT * 512) return;
  const int kc   = idx >> 9;
  const int cg   = (idx >> 2) & 127;
  const int gate = idx & 3;
  const int row  = (gate == 0) ? cg : (gate == 1) ? cg + 128 : cg + 256;
  float v = 0.f;
  if (kc < KXP) {
    if (kc < KXW && gate != 3) v = Wih[row * KXW + kc];   // r,z,i_n use Wih
  } else {
    if (gate != 2) v = Whh[row * 128 + (kc - KXP)];        // r,z,h_n use Whh
  }
  WT[idx] = v;
}

__global__ __launch_bounds__(256) void prep_bias(
    const float* __restrict__ bih, const float* __restrict__ bhh,
    float* __restrict__ bias)
{
  const int idx = blockIdx.x * 256 + threadIdx.x;
  if (idx >= 512) return;
  const int cg = idx >> 2, gate = idx & 3;
  float v;
  if (gate == 0)      v = bih[cg]       + bhh[cg];
  else if (gate == 1) v = bih[cg + 128] + bhh[cg + 128];
  else if (gate == 2) v = bih[cg + 256];
  else                v = bhh[cg + 256];
  bias[idx] = v;
}

__global__ __launch_bounds__(256) void prep_encWT(
    const float* __restrict__ W, float* __restrict__ WT, int KW, int KP)
{
  const int idx = blockIdx.x * 256 + threadIdx.x;
  if (idx >= KP * 128) return;
  const int kc = idx >> 7, c = idx & 127;
  WT[idx] = (kc < KW) ? W[c * KW + kc] : 0.f;
}

// ---------------------------------------------------------------------------
// Fused GRU kernel: 16 rows x 512 interleaved cols per 256-thread block.
// MODE 0: edge update (in-place e_h), MODE 1: node update (in-place h),
// MODE 2: global update (h_prev = 0, writes g).
// ---------------------------------------------------------------------------
template<int MODE, int KXC, int KHC, class T>
__global__ __launch_bounds__(256) void gru_kernel(
    const float* __restrict__ towers,
    const T* __restrict__ hstate,
    const T* __restrict__ estate,
    T* __restrict__ outstate,
    const float* __restrict__ hsum,
    const float* __restrict__ esum,
    const float* __restrict__ WT,
    const float* __restrict__ bias)
{
  constexpr int KT  = (KXC + KHC) * 16;   // total k slots
  constexpr int KXP = KXC * 16;           // padded x length
  __shared__ float4 ATl4[KT * 4];         // A transposed: [kc][16 rows]
  __shared__ float4 Bl4[16 * 128];        // B chunk: [16 kc][128 cg][4 gates]
  float* ATl = (float*)ATl4;
  const int t = threadIdx.x;
  const int rowBase = blockIdx.x * 16;

  // ---- stage gathered input rows (transposed) into LDS ----
  for (int idx = t; idx < KT * 16; idx += 256) {
    const int kc = idx >> 4;
    const int r  = idx & 15;
    const int grow = rowBase + r;
    float v = 0.f;
    if (MODE == 0) {                       // x = [t_i, h_i, t_j, h_j], h = e_h
      const int n = grow >> 6, i = (grow >> 3) & 7, j = grow & 7;
      if (kc < 14)        v = towers[(n * 8 + i) * 14 + kc];
      else if (kc < 142)  v = Cvt<T>::to(hstate[(n * 8 + i) * 128 + (kc - 14)]);
      else if (kc < 156)  v = towers[(n * 8 + j) * 14 + (kc - 142)];
      else if (kc < 284)  v = Cvt<T>::to(hstate[(n * 8 + j) * 128 + (kc - 156)]);
      else if (kc >= 288) v = Cvt<T>::to(estate[grow * 128 + (kc - 288)]);
    } else if (MODE == 1) {                // x = [towers, edges], h = h
      const int i = grow & 7;
      if (kc < 14)        v = towers[grow * 14 + kc];
      else if (kc < 142)  v = (i < 7) ? Cvt<T>::to(estate[(grow * 8 + i + 1) * 128 + (kc - 14)]) : 0.f;
      else if (kc >= 160) v = Cvt<T>::to(hstate[grow * 128 + (kc - 160)]);
    } else {                               // x = [hsum, esum], h = 0
      if (kc < 128)       v = hsum[grow * 128 + kc];
      else if (kc < 256)  v = esum[grow * 128 + (kc - 128)];
    }
    ATl[idx] = v;
  }

  const int c  = t & 127;                  // column group (= h index)
  const int rh = t >> 7;                   // row half (8 rows each)
  float accR[8], accZ[8], accN1[8], accN2[8];
  #pragma unroll
  for (int rr = 0; rr < 8; ++rr) { accR[rr] = 0.f; accZ[rr] = 0.f; accN1[rr] = 0.f; accN2[rr] = 0.f; }

  const float4* WT4 = (const float4*)WT;
  for (int ck = 0; ck < KXC + KHC; ++ck) {
    __syncthreads();                       // Bl reuse / initial A staging
    #pragma unroll
    for (int ii = 0; ii < 8; ++ii) {
      const int idx = t + ii * 256;        // 2048 float4 per chunk
      Bl4[idx] = WT4[ck * 2048 + idx];
    }
    __syncthreads();
    const int kb = ck * 16;
    if (ck < KXC) {                        // x phase: gates r, z, i_n
      #pragma unroll
      for (int kcl = 0; kcl < 16; ++kcl) {
        const float4 w  = Bl4[kcl * 128 + c];
        const float4 a0 = ATl4[(kb + kcl) * 4 + rh * 2];
        const float4 a1 = ATl4[(kb + kcl) * 4 + rh * 2 + 1];
        const float av[8] = {a0.x, a0.y, a0.z, a0.w, a1.x, a1.y, a1.z, a1.w};
        #pragma unroll
        for (int rr = 0; rr < 8; ++rr) {
          accR[rr]  += w.x * av[rr];
          accZ[rr]  += w.y * av[rr];
          accN1[rr] += w.z * av[rr];
        }
      }
    } else {                               // h phase: gates r, z, h_n
      #pragma unroll
      for (int kcl = 0; kcl < 16; ++kcl) {
        const float4 w  = Bl4[kcl * 128 + c];
        const float4 a0 = ATl4[(kb + kcl) * 4 + rh * 2];
        const float4 a1 = ATl4[(kb + kcl) * 4 + rh * 2 + 1];
        const float av[8] = {a0.x, a0.y, a0.z, a0.w, a1.x, a1.y, a1.z, a1.w};
        #pragma unroll
        for (int rr = 0; rr < 8; ++rr) {
          accR[rr]  += w.x * av[rr];
          accZ[rr]  += w.y * av[rr];
          accN2[rr] += w.w * av[rr];
        }
      }
    }
  }

  // ---- GRU epilogue ----
  const float4 bb = ((const float4*)bias)[c];
  #pragma unroll
  for (int rr = 0; rr < 8; ++rr) {
    const int r = rh * 8 + rr;
    const int grow = rowBase + r;
    const float hprev = ATl[(KXP + c) * 16 + r];   // staged h (0 for MODE 2)
    const float rg = sigmoid_f(accR[rr] + bb.x);
    const float zg = sigmoid_f(accZ[rr] + bb.y);
    const float nn = tanh_f(accN1[rr] + bb.z + rg * (accN2[rr] + bb.w));
    outstate[grow * 128 + c] = Cvt<T>::from((1.f - zg) * nn + zg * hprev);
  }
}

// ---------------------------------------------------------------------------
// 2-layer tanh MLP encoder (E_n: KX=16, E_e: KX=32), 16 rows per block.
// ---------------------------------------------------------------------------
template<int KX, int EE, class T>
__global__ __launch_bounds__(256) void mlp2_kernel(
    const float* __restrict__ towers,
    const float* __restrict__ W1T, const float* __restrict__ b1,
    const float* __restrict__ W2T, const float* __restrict__ b2,
    T* __restrict__ dst)
{
  __shared__ float4 XT4[KX * 4];
  __shared__ float4 Z1T4[128 * 4];
  float* XT  = (float*)XT4;
  float* Z1T = (float*)Z1T4;
  const int t = threadIdx.x;
  const int rowBase = blockIdx.x * 16;

  for (int idx = t; idx < KX * 16; idx += 256) {
    const int kc = idx >> 4, r = idx & 15, grow = rowBase + r;
    float v = 0.f;
    if (EE) {
      const int n = grow >> 6, i = (grow >> 3) & 7, j = grow & 7;
      if (kc < 14)      v = towers[(n * 8 + i) * 14 + kc];
      else if (kc < 28) v = towers[(n * 8 + j) * 14 + (kc - 14)];
    } else {
      if (kc < 14)      v = towers[grow * 14 + kc];
    }
    XT[idx] = v;
  }
  __syncthreads();

  const int c = t & 127, rh = t >> 7;
  float acc[8];
  #pragma unroll
  for (int rr = 0; rr < 8; ++rr) acc[rr] = 0.f;
  for (int kc = 0; kc < KX; ++kc) {
    const float w  = W1T[kc * 128 + c];
    const float4 a0 = XT4[kc * 4 + rh * 2];
    const float4 a1 = XT4[kc * 4 + rh * 2 + 1];
    const float av[8] = {a0.x, a0.y, a0.z, a0.w, a1.x, a1.y, a1.z, a1.w};
    #pragma unroll
    for (int rr = 0; rr < 8; ++rr) acc[rr] += w * av[rr];
  }
  const float bb1 = b1[c];
  #pragma unroll
  for (int rr = 0; rr < 8; ++rr)
    Z1T[c * 16 + rh * 8 + rr] = tanh_f(acc[rr] + bb1);
  __syncthreads();

  #pragma unroll
  for (int rr = 0; rr < 8; ++rr) acc[rr] = 0.f;
  for (int kc = 0; kc < 128; ++kc) {
    const float w  = W2T[kc * 128 + c];
    const float4 a0 = Z1T4[kc * 4 + rh * 2];
    const float4 a1 = Z1T4[kc * 4 + rh * 2 + 1];
    const float av[8] = {a0.x, a0.y, a0.z, a0.w, a1.x, a1.y, a1.z, a1.w};
    #pragma unroll
    for (int rr = 0; rr < 8; ++rr) acc[rr] += w * av[rr];
  }
  const float bb2 = b2[c];
  #pragma unroll
  for (int rr = 0; rr < 8; ++rr)
    dst[(rowBase + rh * 8 + rr) * 128 + c] = Cvt<T>::from(tanh_f(acc[rr] + bb2));
}

template<class T>
__global__ __launch_bounds__(256) void sums_kernel(
    const T* __restrict__ h, const T* __restrict__ eh,
    float* __restrict__ hsum, float* __restrict__ esum)
{
  const int idx = blockIdx.x * 256 + threadIdx.x;  // < 4096*128
  const int n = idx >> 7, hh = idx & 127;
  float hs = 0.f, es = 0.f;
  #pragma unroll
  for (int i = 0; i < 8; ++i) hs += Cvt<T>::to(h[(n * 8 + i) * 128 + hh]);
  #pragma unroll
  for (int i = 0; i < 7; ++i) es += Cvt<T>::to(eh[((n * 8 + i) * 8 + i + 1) * 128 + hh]);
  hsum[idx] = hs;
  esum[idx] = es;
}

template<class T>
__global__ __launch_bounds__(256) void out_kernel(
    const T* __restrict__ g, const float* __restrict__ OW,
    const float* __restrict__ Ob, float* __restrict__ out)
{
  const int n = blockIdx.x * 4 + (threadIdx.x >> 6);
  const int lane = threadIdx.x & 63;
  float p = Cvt<T>::to(g[n * 128 + lane]) * OW[lane]
          + Cvt<T>::to(g[n * 128 + 64 + lane]) * OW[64 + lane];
  #pragma unroll
  for (int off = 32; off > 0; off >>= 1) p += __shfl_down(p, off, 64);
  if (lane == 0) out[n] = sigmoid_f(p + Ob[0]);
}

// ---------------------------------------------------------------------------
template<class T>
static void run_all(void* const* d_in, void* d_out, void* d_ws, hipStream_t stream)
{
  const float* towers = (const float*)d_in[0];
  const float* EnW1 = (const float*)d_in[1];
  const float* EnB1 = (const float*)d_in[2];
  const float* EnW2 = (const float*)d_in[3];
  const float* EnB2 = (const float*)d_in[4];
  const float* EeW1 = (const float*)d_in[5];
  const float* EeB1 = (const float*)d_in[6];
  const float* EeW2 = (const float*)d_in[7];
  const float* EeB2 = (const float*)d_in[8];
  const float* UWih = (const float*)d_in[9];
  const float* UWhh = (const float*)d_in[10];
  const float* UBih = (const float*)d_in[11];
  const float* UBhh = (const float*)d_in[12];
  const float* MWih = (const float*)d_in[13];
  const float* MWhh = (const float*)d_in[14];
  const float* MBih = (const float*)d_in[15];
  const float* MBhh = (const float*)d_in[16];
  const float* GWih = (const float*)d_in[17];
  const float* GWhh = (const float*)d_in[18];
  const float* GBih = (const float*)d_in[19];
  const float* GBhh = (const float*)d_in[20];
  const float* OW   = (const float*)d_in[21];
  const float* Ob   = (const float*)d_in[22];

  char* ws = (char*)d_ws;
  size_t off = 0;
  auto take = [&](size_t b) { void* p = ws + off; off = (off + b + 255) & ~(size_t)255; return p; };
  T* h  = (T*)take((size_t)32768 * 128 * sizeof(T));
  T* eh = (T*)take((size_t)262144 * 128 * sizeof(T));
  T* g  = (T*)take((size_t)4096 * 128 * sizeof(T));
  float* hsum = (float*)take((size_t)4096 * 128 * 4);
  float* esum = (float*)take((size_t)4096 * 128 * 4);
  float* WT_M = (float*)take((size_t)416 * 512 * 4);
  float* WT_U = (float*)take((size_t)288 * 512 * 4);
  float* WT_G = (float*)take((size_t)384 * 512 * 4);
  float* bias_M = (float*)take(512 * 4);
  float* bias_U = (float*)take(512 * 4);
  float* bias_G = (float*)take(512 * 4);
  float* W1T_en = (float*)take((size_t)16 * 128 * 4);
  float* W2T_en = (float*)take((size_t)128 * 128 * 4);
  float* W1T_ee = (float*)take((size_t)32 * 128 * 4);
  float* W2T_ee = (float*)take((size_t)128 * 128 * 4);

  // weight prep
  prep_gruWT<<<832, 256, 0, stream>>>(MWih, MWhh, WT_M, 284, 288, 416);
  prep_gruWT<<<576, 256, 0, stream>>>(UWih, UWhh, WT_U, 142, 160, 288);
  prep_gruWT<<<768, 256, 0, stream>>>(GWih, GWhh, WT_G, 256, 256, 384);
  prep_bias<<<2, 256, 0, stream>>>(MBih, MBhh, bias_M);
  prep_bias<<<2, 256, 0, stream>>>(UBih, UBhh, bias_U);
  prep_bias<<<2, 256, 0, stream>>>(GBih, GBhh, bias_G);
  prep_encWT<<<8, 256, 0, stream>>>(EnW1, W1T_en, 14, 16);
  prep_encWT<<<64, 256, 0, stream>>>(EnW2, W2T_en, 128, 128);
  prep_encWT<<<16, 256, 0, stream>>>(EeW1, W1T_ee, 28, 32);
  prep_encWT<<<64, 256, 0, stream>>>(EeW2, W2T_ee, 128, 128);

  // encoders
  mlp2_kernel<16, 0, T><<<2048, 256, 0, stream>>>(towers, W1T_en, EnB1, W2T_en, EnB2, h);
  mlp2_kernel<32, 1, T><<<16384, 256, 0, stream>>>(towers, W1T_ee, EeB1, W2T_ee, EeB2, eh);

  // k = 3 message-passing iterations (harness always uses k=3)
  for (int it = 0; it < 3; ++it) {
    gru_kernel<0, 18, 8, T><<<16384, 256, 0, stream>>>(towers, h, eh, eh, nullptr, nullptr, WT_M, bias_M);
    gru_kernel<1, 10, 8, T><<<2048, 256, 0, stream>>>(towers, h, eh, h, nullptr, nullptr, WT_U, bias_U);
  }

  // global readout
  sums_kernel<T><<<2048, 256, 0, stream>>>(h, eh, hsum, esum);
  gru_kernel<2, 16, 8, T><<<256, 256, 0, stream>>>(towers, (const T*)nullptr, (const T*)nullptr, g,
                                                   hsum, esum, WT_G, bias_G);
  out_kernel<T><<<1024, 256, 0, stream>>>(g, OW, Ob, (float*)d_out);
}

extern "C" void kernel_launch(void* const* d_in, const int* in_sizes, int n_in,
                              void* d_out, int out_size, void* d_ws, size_t ws_size,
                              hipStream_t stream)
{
  (void)in_sizes; (void)n_in; (void)out_size;
  // fp32-state footprint ~159.7 MB; bf16-state fallback ~83 MB
  if (ws_size >= 161000000ULL) run_all<float>(d_in, d_out, d_ws, stream);
  else                         run_all<bf16>(d_in, d_out, d_ws, stream);
}

// Round 3
// 691.883 us; speedup vs baseline: 9.7911x; 9.7911x over previous
//
#include <hip/hip_runtime.h>
#include <hip/hip_bf16.h>

typedef __hip_bfloat16 bf16;
typedef unsigned short ush;
typedef short s16x8 __attribute__((ext_vector_type(8)));
typedef float f32x4 __attribute__((ext_vector_type(4)));

#define DEV __device__ __forceinline__

DEV float sigmoid_f(float x) { return 1.f / (1.f + __expf(-x)); }
DEV float tanh_f(float x) { return 1.f - 2.f / (__expf(2.f * x) + 1.f); }

DEV float u2f(ush u) { unsigned int v = ((unsigned int)u) << 16; float f; __builtin_memcpy(&f, &v, 4); return f; }
DEV ush f2u(float f) { bf16 h = __float2bfloat16(f); ush u; __builtin_memcpy(&u, &h, 2); return u; }

DEV f32x4 MFMA(s16x8 a, s16x8 b, f32x4 c) {
  return __builtin_amdgcn_mfma_f32_16x16x32_bf16(a, b, c, 0, 0, 0);
}

// swizzled element index within a [rows][32] bf16 chunk: 16B blocks XOR'd by (row>>1)&3
DEV int swz_idx(int row, int kk) { return row * 32 + (((kk >> 3) ^ ((row >> 1) & 3)) << 3) + (kk & 7); }
DEV int swz_blk(int row, int blk) { return row * 32 + ((blk ^ ((row >> 1) & 3)) << 3); }

// ---------------------------------------------------------------------------
// Constants: N=4096 graphs, K=8 nodes, n_in=14, H=128, k=3 iters. All inputs fp32.
// xh buffer: [32768][144] bf16 = [towers(14), pad(2), h(128)]
// eh buffer: [262144][128] bf16
// Edge GRU A k-layout (416 = 13 chunks): [xh_i(144) | xh_j(144)] (288, 9 chunks) + e_h(128, 4 chunks)
// Node GRU A k-layout (288 = 9 chunks): [t(16), edges(128), pad(16)] (160, 5 chunks) + h(128, 4 chunks)
// Weight layout WT[chunk][n=gate*128+c][kk=32] bf16, pre-transposed + swizzled.
// ---------------------------------------------------------------------------

__global__ __launch_bounds__(256) void prep_xh_t(const float* __restrict__ towers, ush* __restrict__ xh) {
  const int idx = blockIdx.x * 256 + threadIdx.x;   // 32768*16
  if (idx >= 32768 * 16) return;
  const int row = idx >> 4, kk = idx & 15;
  xh[row * 144 + kk] = f2u(kk < 14 ? towers[row * 14 + kk] : 0.f);
}

__global__ __launch_bounds__(256) void prep_WTe(const float* __restrict__ Wih, const float* __restrict__ Whh,
                                                ush* __restrict__ dst) {
  const int idx = blockIdx.x * 256 + threadIdx.x;   // 13*512*32 = 212992
  if (idx >= 13 * 512 * 32) return;
  const int ck = idx >> 14, n = (idx >> 5) & 511, kk = idx & 31;
  const int k = ck * 32 + kk, gate = n >> 7, c = n & 127;
  float w = 0.f;
  const int row = (gate == 0) ? c : (gate == 1) ? 128 + c : 256 + c;
  if (k < 288) {            // x region -> M_Wih (284 cols: t_i,h_i,t_j,h_j)
    int col = -1;
    if (k < 16)        { if (k < 14) col = k; }
    else if (k < 144)  col = 14 + (k - 16);
    else if (k < 160)  { if (k - 144 < 14) col = 142 + (k - 144); }
    else               col = 156 + (k - 160);
    if (gate != 3 && col >= 0) w = Wih[row * 284 + col];
  } else {                  // h region -> M_Whh
    if (gate != 2) w = Whh[row * 128 + (k - 288)];
  }
  dst[ck * 16384 + swz_idx(n, kk)] = f2u(w);
}

__global__ __launch_bounds__(256) void prep_WTu(const float* __restrict__ Wih, const float* __restrict__ Whh,
                                                ush* __restrict__ dst) {
  const int idx = blockIdx.x * 256 + threadIdx.x;   // 9*512*32 = 147456
  if (idx >= 9 * 512 * 32) return;
  const int ck = idx >> 14, n = (idx >> 5) & 511, kk = idx & 31;
  const int k = ck * 32 + kk, gate = n >> 7, c = n & 127;
  float w = 0.f;
  const int row = (gate == 0) ? c : (gate == 1) ? 128 + c : 256 + c;
  if (k < 160) {            // x region -> U_Wih (142 cols: t, edges)
    int col = -1;
    if (k < 16)        { if (k < 14) col = k; }
    else if (k < 144)  col = 14 + (k - 16);
    if (gate != 3 && col >= 0) w = Wih[row * 142 + col];
  } else {                  // h region -> U_Whh
    if (gate != 2) w = Whh[row * 128 + (k - 160)];
  }
  dst[ck * 16384 + swz_idx(n, kk)] = f2u(w);
}

// mode 0: 128x14 (En_W1, K pad 32); mode 1: 128x28 pair (Ee_W1); mode 2: 128x128 dense (4 chunks)
__global__ __launch_bounds__(256) void prep_wb(const float* __restrict__ W, ush* __restrict__ dst,
                                               int mode, int nelem) {
  const int idx = blockIdx.x * 256 + threadIdx.x;
  if (idx >= nelem) return;
  const int ck = idx >> 12, n = (idx >> 5) & 127, kk = idx & 31;
  float w = 0.f;
  if (mode == 2)      w = W[n * 128 + ck * 32 + kk];
  else if (mode == 0) { if (kk < 14) w = W[n * 14 + kk]; }
  else {
    int col = (kk < 16) ? (kk < 14 ? kk : -1) : (kk < 30 ? 14 + (kk - 16) : -1);
    if (col >= 0) w = W[n * 28 + col];
  }
  dst[ck * 4096 + swz_idx(n, kk)] = f2u(w);
}

__global__ __launch_bounds__(256) void prep_bias4(const float* __restrict__ bih, const float* __restrict__ bhh,
                                                  float* __restrict__ dst) {
  const int idx = blockIdx.x * 256 + threadIdx.x;
  if (idx >= 512) return;
  const int g = idx >> 7, c = idx & 127;
  float v;
  if (g == 0)      v = bih[c] + bhh[c];
  else if (g == 1) v = bih[128 + c] + bhh[128 + c];
  else if (g == 2) v = bih[256 + c];
  else             v = bhh[256 + c];
  dst[idx] = v;
}

// ---------------------------------------------------------------------------
// MFMA GRU: 64 rows x 512 gate-cols per 256-thread block; wave w owns H-cols
// [32w,32w+32) of all 4 gates. MODE 0 = edge (in-place eh), MODE 1 = node
// (in-place xh h-part).
// ---------------------------------------------------------------------------
template<int MODE>
__global__ __launch_bounds__(256, 2) void gru_mfma(
    ush* __restrict__ xh, ush* __restrict__ eh,
    const ush* __restrict__ WT, const float* __restrict__ bias)
{
  constexpr int NCH = (MODE == 0) ? 13 : 9;   // total K chunks
  constexpr int XCH = (MODE == 0) ? 9 : 5;    // x-phase chunks
  __shared__ ush As[64 * 32];
  __shared__ ush Bs[512 * 32];
  const int t = threadIdx.x, lane = t & 63, w = t >> 6;
  const int rowBase = blockIdx.x * 64;
  const int gm = t >> 2, gb = t & 3, grow = rowBase + gm;

  f32x4 accR[4][2], accZ[4][2], accN1[4][2], accN2[4][2];
  #pragma unroll
  for (int rt = 0; rt < 4; ++rt)
    #pragma unroll
    for (int s = 0; s < 2; ++s) {
      #pragma unroll
      for (int q = 0; q < 4; ++q) { accR[rt][s][q] = 0.f; accZ[rt][s][q] = 0.f; accN1[rt][s][q] = 0.f; accN2[rt][s][q] = 0.f; }
    }

  for (int ck = 0; ck < NCH; ++ck) {
    // ---- stage B chunk (linear copy of pre-swizzled weights) ----
    const ush* wsrc = WT + ck * 16384;
    #pragma unroll
    for (int ii = 0; ii < 8; ++ii) {
      const int o = (t + ii * 256) * 8;
      *(s16x8*)&Bs[o] = *(const s16x8*)&wsrc[o];
    }
    // ---- stage A chunk (gather, 16B per thread, swizzled store) ----
    {
      const int k0 = ck * 32 + gb * 8;
      s16x8 v;
      #pragma unroll
      for (int z = 0; z < 8; ++z) v[z] = 0;
      if (MODE == 0) {
        const int n = grow >> 6, i = (grow >> 3) & 7, j = grow & 7;
        const ush* src;
        if (k0 < 144)      src = xh + (n * 8 + i) * 144 + k0;
        else if (k0 < 288) src = xh + (n * 8 + j) * 144 + (k0 - 144);
        else               src = eh + grow * 128 + (k0 - 288);
        v = *(const s16x8*)src;
      } else {
        if (k0 < 16)       v = *(const s16x8*)(xh + grow * 144 + k0);
        else if (k0 < 144) {
          const int i = grow & 7;
          if (i < 7) v = *(const s16x8*)(eh + (grow * 8 + i + 1) * 128 + (k0 - 16));
        } else if (k0 >= 160) {
          v = *(const s16x8*)(xh + grow * 144 + 16 + (k0 - 160));
        }                  // 144..159: zero pad
      }
      *(s16x8*)&As[swz_blk(gm, gb)] = v;
    }
    __syncthreads();

    // ---- fragments + MFMA ----
    s16x8 af[4];
    #pragma unroll
    for (int rt = 0; rt < 4; ++rt) {
      const int m = rt * 16 + (lane & 15);
      af[rt] = *(const s16x8*)&As[swz_blk(m, lane >> 4)];
    }
    if (ck < XCH) {                    // gates r, z, n1
      #pragma unroll
      for (int s = 0; s < 2; ++s) {
        const int nb = w * 32 + s * 16 + (lane & 15);
        const s16x8 bR = *(const s16x8*)&Bs[swz_blk(0 * 128 + nb, lane >> 4)];
        const s16x8 bZ = *(const s16x8*)&Bs[swz_blk(1 * 128 + nb, lane >> 4)];
        const s16x8 bN = *(const s16x8*)&Bs[swz_blk(2 * 128 + nb, lane >> 4)];
        #pragma unroll
        for (int rt = 0; rt < 4; ++rt) {
          accR[rt][s]  = MFMA(af[rt], bR, accR[rt][s]);
          accZ[rt][s]  = MFMA(af[rt], bZ, accZ[rt][s]);
          accN1[rt][s] = MFMA(af[rt], bN, accN1[rt][s]);
        }
      }
    } else {                           // gates r, z, n2
      #pragma unroll
      for (int s = 0; s < 2; ++s) {
        const int nb = w * 32 + s * 16 + (lane & 15);
        const s16x8 bR = *(const s16x8*)&Bs[swz_blk(0 * 128 + nb, lane >> 4)];
        const s16x8 bZ = *(const s16x8*)&Bs[swz_blk(1 * 128 + nb, lane >> 4)];
        const s16x8 bN = *(const s16x8*)&Bs[swz_blk(3 * 128 + nb, lane >> 4)];
        #pragma unroll
        for (int rt = 0; rt < 4; ++rt) {
          accR[rt][s]  = MFMA(af[rt], bR, accR[rt][s]);
          accZ[rt][s]  = MFMA(af[rt], bZ, accZ[rt][s]);
          accN2[rt][s] = MFMA(af[rt], bN, accN2[rt][s]);
        }
      }
    }
    __syncthreads();
  }

  // ---- GRU epilogue (in-lane: all 4 gates share (row,col) per lane) ----
  #pragma unroll
  for (int s = 0; s < 2; ++s) {
    const int hcol = w * 32 + s * 16 + (lane & 15);
    const float bR = bias[hcol], bZ = bias[128 + hcol], bN1 = bias[256 + hcol], bN2 = bias[384 + hcol];
    #pragma unroll
    for (int rt = 0; rt < 4; ++rt) {
      #pragma unroll
      for (int q = 0; q < 4; ++q) {
        const int row = rowBase + rt * 16 + (lane >> 4) * 4 + q;
        float hp;
        if (MODE == 0) hp = u2f(eh[row * 128 + hcol]);
        else           hp = u2f(xh[row * 144 + 16 + hcol]);
        const float rg = sigmoid_f(accR[rt][s][q] + bR);
        const float zg = sigmoid_f(accZ[rt][s][q] + bZ);
        const float nn = tanh_f(accN1[rt][s][q] + bN1 + rg * (accN2[rt][s][q] + bN2));
        const float o = (1.f - zg) * nn + zg * hp;
        if (MODE == 0) eh[row * 128 + hcol] = f2u(o);
        else           xh[row * 144 + 16 + hcol] = f2u(o);
      }
    }
  }
}

// ---------------------------------------------------------------------------
// MFMA 2-layer tanh encoder. MODE 0 = En (node rows -> xh h-part),
// MODE 1 = Ee (edge pairs -> eh). 64 rows/block, N=128, l1 K=32, l2 K=128.
// ---------------------------------------------------------------------------
template<int MODE>
__global__ __launch_bounds__(256, 2) void enc_mfma(
    ush* __restrict__ xh, ush* __restrict__ eh,
    const ush* __restrict__ WB1, const float* __restrict__ b1,
    const ush* __restrict__ WB2, const float* __restrict__ b2)
{
  __shared__ ush A1[64 * 32];
  __shared__ ush Z1[4 * 64 * 32];
  __shared__ ush B1s[128 * 32];
  __shared__ ush B2s[4 * 128 * 32];
  const int t = threadIdx.x, lane = t & 63, w = t >> 6;
  const int rowBase = blockIdx.x * 64;

  #pragma unroll
  for (int ii = 0; ii < 2; ++ii) { const int o = (t + ii * 256) * 8; *(s16x8*)&B1s[o] = *(const s16x8*)&WB1[o]; }
  #pragma unroll
  for (int ii = 0; ii < 8; ++ii) { const int o = (t + ii * 256) * 8; *(s16x8*)&B2s[o] = *(const s16x8*)&WB2[o]; }
  {
    const int gm = t >> 2, gb = t & 3, grow = rowBase + gm;
    s16x8 v;
    #pragma unroll
    for (int z = 0; z < 8; ++z) v[z] = 0;
    if (MODE == 0) {
      if (gb < 2) v = *(const s16x8*)(xh + grow * 144 + gb * 8);
    } else {
      const int n = grow >> 6, i = (grow >> 3) & 7, j = grow & 7;
      v = (gb < 2) ? *(const s16x8*)(xh + (n * 8 + i) * 144 + gb * 8)
                   : *(const s16x8*)(xh + (n * 8 + j) * 144 + (gb - 2) * 8);
    }
    *(s16x8*)&A1[swz_blk(gm, gb)] = v;
  }
  __syncthreads();

  // layer 1
  s16x8 af[4];
  #pragma unroll
  for (int rt = 0; rt < 4; ++rt) {
    const int m = rt * 16 + (lane & 15);
    af[rt] = *(const s16x8*)&A1[swz_blk(m, lane >> 4)];
  }
  f32x4 acc1[4][2];
  #pragma unroll
  for (int rt = 0; rt < 4; ++rt)
    #pragma unroll
    for (int ct = 0; ct < 2; ++ct) {
      #pragma unroll
      for (int q = 0; q < 4; ++q) acc1[rt][ct][q] = 0.f;
    }
  #pragma unroll
  for (int ct = 0; ct < 2; ++ct) {
    const int n = w * 32 + ct * 16 + (lane & 15);
    const s16x8 bf = *(const s16x8*)&B1s[swz_blk(n, lane >> 4)];
    #pragma unroll
    for (int rt = 0; rt < 4; ++rt) acc1[rt][ct] = MFMA(af[rt], bf, acc1[rt][ct]);
  }
  // tanh -> Z1 (A-layout for layer 2, swizzled)
  #pragma unroll
  for (int ct = 0; ct < 2; ++ct) {
    const int col = w * 32 + ct * 16 + (lane & 15);
    const int ck2 = col >> 5, kk = col & 31;
    #pragma unroll
    for (int rt = 0; rt < 4; ++rt) {
      #pragma unroll
      for (int q = 0; q < 4; ++q) {
        const int m = rt * 16 + (lane >> 4) * 4 + q;
        Z1[ck2 * 2048 + swz_idx(m, kk)] = f2u(tanh_f(acc1[rt][ct][q] + b1[col]));
      }
    }
  }
  __syncthreads();

  // layer 2
  f32x4 acc2[4][2];
  #pragma unroll
  for (int rt = 0; rt < 4; ++rt)
    #pragma unroll
    for (int ct = 0; ct < 2; ++ct) {
      #pragma unroll
      for (int q = 0; q < 4; ++q) acc2[rt][ct][q] = 0.f;
    }
  for (int ck2 = 0; ck2 < 4; ++ck2) {
    #pragma unroll
    for (int rt = 0; rt < 4; ++rt) {
      const int m = rt * 16 + (lane & 15);
      af[rt] = *(const s16x8*)&Z1[ck2 * 2048 + swz_blk(m, lane >> 4)];
    }
    #pragma unroll
    for (int ct = 0; ct < 2; ++ct) {
      const int n = w * 32 + ct * 16 + (lane & 15);
      const s16x8 bf = *(const s16x8*)&B2s[ck2 * 4096 + swz_blk(n, lane >> 4)];
      #pragma unroll
      for (int rt = 0; rt < 4; ++rt) acc2[rt][ct] = MFMA(af[rt], bf, acc2[rt][ct]);
    }
  }
  // epilogue
  #pragma unroll
  for (int ct = 0; ct < 2; ++ct) {
    const int col = w * 32 + ct * 16 + (lane & 15);
    #pragma unroll
    for (int rt = 0; rt < 4; ++rt) {
      #pragma unroll
      for (int q = 0; q < 4; ++q) {
        const int row = rowBase + rt * 16 + (lane >> 4) * 4 + q;
        const float v = tanh_f(acc2[rt][ct][q] + b2[col]);
        if (MODE == 0) xh[row * 144 + 16 + col] = f2u(v);
        else           eh[row * 128 + col] = f2u(v);
      }
    }
  }
}

// ---------------------------------------------------------------------------
// readout path (small): sums, global GRU (fp32 VALU kernel), output head
// ---------------------------------------------------------------------------
__global__ __launch_bounds__(256) void sums2(const ush* __restrict__ xh, const ush* __restrict__ eh,
                                             float* __restrict__ hsum, float* __restrict__ esum) {
  const int idx = blockIdx.x * 256 + threadIdx.x;    // 4096*128
  const int n = idx >> 7, hh = idx & 127;
  float hs = 0.f, es = 0.f;
  #pragma unroll
  for (int i = 0; i < 8; ++i) hs += u2f(xh[(n * 8 + i) * 144 + 16 + hh]);
  #pragma unroll
  for (int i = 0; i < 7; ++i) es += u2f(eh[((n * 8 + i) * 8 + i + 1) * 128 + hh]);
  hsum[idx] = hs;
  esum[idx] = es;
}

__global__ __launch_bounds__(256) void prep_gruWT_G(const float* __restrict__ Wih, const float* __restrict__ Whh,
                                                    float* __restrict__ WT) {
  const int idx = blockIdx.x * 256 + threadIdx.x;    // 384*512
  if (idx >= 384 * 512) return;
  const int kc = idx >> 9, cg = (idx >> 2) & 127, gate = idx & 3;
  const int row = (gate == 0) ? cg : (gate == 1) ? cg + 128 : cg + 256;
  float v = 0.f;
  if (kc < 256) { if (gate != 3) v = Wih[row * 256 + kc]; }
  else          { if (gate != 2) v = Whh[row * 128 + (kc - 256)]; }
  WT[idx] = v;
}

__global__ __launch_bounds__(256) void prep_biasG(const float* __restrict__ bih, const float* __restrict__ bhh,
                                                  float* __restrict__ bias) {
  const int idx = blockIdx.x * 256 + threadIdx.x;
  if (idx >= 512) return;
  const int cg = idx >> 2, gate = idx & 3;
  float v;
  if (gate == 0)      v = bih[cg] + bhh[cg];
  else if (gate == 1) v = bih[cg + 128] + bhh[cg + 128];
  else if (gate == 2) v = bih[cg + 256];
  else                v = bhh[cg + 256];
  bias[idx] = v;
}

// global GRU: 16 rows x 512 interleaved cols per block, fp32 VALU (h_prev = 0)
__global__ __launch_bounds__(256) void gru_global(
    const float* __restrict__ hsum, const float* __restrict__ esum,
    float* __restrict__ g, const float* __restrict__ WT, const float* __restrict__ bias)
{
  constexpr int KT = 384;
  __shared__ float4 ATl4[KT * 4];
  __shared__ float4 Bl4[16 * 128];
  float* ATl = (float*)ATl4;
  const int t = threadIdx.x;
  const int rowBase = blockIdx.x * 16;
  for (int idx = t; idx < KT * 16; idx += 256) {
    const int kc = idx >> 4, r = idx & 15, grow = rowBase + r;
    float v = 0.f;
    if (kc < 128)      v = hsum[grow * 128 + kc];
    else if (kc < 256) v = esum[grow * 128 + (kc - 128)];
    ATl[idx] = v;
  }
  const int c = t & 127, rh = t >> 7;
  float accR[8], accZ[8], accN1[8];
  #pragma unroll
  for (int rr = 0; rr < 8; ++rr) { accR[rr] = 0.f; accZ[rr] = 0.f; accN1[rr] = 0.f; }
  const float4* WT4 = (const float4*)WT;
  for (int ck = 0; ck < 16; ++ck) {     // x chunks only (h = 0)
    __syncthreads();
    #pragma unroll
    for (int ii = 0; ii < 8; ++ii) { const int idx = t + ii * 256; Bl4[idx] = WT4[ck * 2048 + idx]; }
    __syncthreads();
    const int kb = ck * 16;
    #pragma unroll
    for (int kcl = 0; kcl < 16; ++kcl) {
      const float4 wv = Bl4[kcl * 128 + c];
      const float4 a0 = ATl4[(kb + kcl) * 4 + rh * 2];
      const float4 a1 = ATl4[(kb + kcl) * 4 + rh * 2 + 1];
      const float av[8] = {a0.x, a0.y, a0.z, a0.w, a1.x, a1.y, a1.z, a1.w};
      #pragma unroll
      for (int rr = 0; rr < 8; ++rr) {
        accR[rr]  += wv.x * av[rr];
        accZ[rr]  += wv.y * av[rr];
        accN1[rr] += wv.z * av[rr];
      }
    }
  }
  const float4 bb = ((const float4*)bias)[c];
  #pragma unroll
  for (int rr = 0; rr < 8; ++rr) {
    const int grow = rowBase + rh * 8 + rr;
    const float rg = sigmoid_f(accR[rr] + bb.x);
    const float zg = sigmoid_f(accZ[rr] + bb.y);
    const float nn = tanh_f(accN1[rr] + bb.z + rg * bb.w);   // h=0 -> h_n = bhh_n
    g[grow * 128 + c] = (1.f - zg) * nn;                      // + zg*0
  }
}

__global__ __launch_bounds__(256) void out_kernel(
    const float* __restrict__ g, const float* __restrict__ OW,
    const float* __restrict__ Ob, float* __restrict__ out)
{
  const int n = blockIdx.x * 4 + (threadIdx.x >> 6);
  const int lane = threadIdx.x & 63;
  float p = g[n * 128 + lane] * OW[lane] + g[n * 128 + 64 + lane] * OW[64 + lane];
  #pragma unroll
  for (int off = 32; off > 0; off >>= 1) p += __shfl_down(p, off, 64);
  if (lane == 0) out[n] = sigmoid_f(p + Ob[0]);
}

// ---------------------------------------------------------------------------
extern "C" void kernel_launch(void* const* d_in, const int* in_sizes, int n_in,
                              void* d_out, int out_size, void* d_ws, size_t ws_size,
                              hipStream_t stream)
{
  (void)in_sizes; (void)n_in; (void)out_size; (void)ws_size;
  const float* towers = (const float*)d_in[0];
  const float* EnW1 = (const float*)d_in[1];
  const float* EnB1 = (const float*)d_in[2];
  const float* EnW2 = (const float*)d_in[3];
  const float* EnB2 = (const float*)d_in[4];
  const float* EeW1 = (const float*)d_in[5];
  const float* EeB1 = (const float*)d_in[6];
  const float* EeW2 = (const float*)d_in[7];
  const float* EeB2 = (const float*)d_in[8];
  const float* UWih = (const float*)d_in[9];
  const float* UWhh = (const float*)d_in[10];
  const float* UBih = (const float*)d_in[11];
  const float* UBhh = (const float*)d_in[12];
  const float* MWih = (const float*)d_in[13];
  const float* MWhh = (const float*)d_in[14];
  const float* MBih = (const float*)d_in[15];
  const float* MBhh = (const float*)d_in[16];
  const float* GWih = (const float*)d_in[17];
  const float* GWhh = (const float*)d_in[18];
  const float* GBih = (const float*)d_in[19];
  const float* GBhh = (const float*)d_in[20];
  const float* OW   = (const float*)d_in[21];
  const float* Ob   = (const float*)d_in[22];

  char* ws = (char*)d_ws;
  size_t off = 0;
  auto take = [&](size_t b) { void* p = ws + off; off = (off + b + 255) & ~(size_t)255; return p; };
  ush*   xh     = (ush*)take((size_t)32768 * 144 * 2);
  ush*   eh     = (ush*)take((size_t)262144 * 128 * 2);
  float* g      = (float*)take((size_t)4096 * 128 * 4);
  float* hsum   = (float*)take((size_t)4096 * 128 * 4);
  float* esum   = (float*)take((size_t)4096 * 128 * 4);
  ush*   WTe    = (ush*)take((size_t)13 * 512 * 32 * 2);
  ush*   WTu    = (ush*)take((size_t)9 * 512 * 32 * 2);
  ush*   WBen1  = (ush*)take((size_t)128 * 32 * 2);
  ush*   WBen2  = (ush*)take((size_t)4 * 128 * 32 * 2);
  ush*   WBee1  = (ush*)take((size_t)128 * 32 * 2);
  ush*   WBee2  = (ush*)take((size_t)4 * 128 * 32 * 2);
  float* biasM  = (float*)take(512 * 4);
  float* biasU  = (float*)take(512 * 4);
  float* WT_G   = (float*)take((size_t)384 * 512 * 4);
  float* biasG  = (float*)take(512 * 4);

  // ---- weight/state prep ----
  prep_xh_t<<<2048, 256, 0, stream>>>(towers, xh);
  prep_WTe<<<832, 256, 0, stream>>>(MWih, MWhh, WTe);
  prep_WTu<<<576, 256, 0, stream>>>(UWih, UWhh, WTu);
  prep_wb<<<16, 256, 0, stream>>>(EnW1, WBen1, 0, 4096);
  prep_wb<<<64, 256, 0, stream>>>(EnW2, WBen2, 2, 16384);
  prep_wb<<<16, 256, 0, stream>>>(EeW1, WBee1, 1, 4096);
  prep_wb<<<64, 256, 0, stream>>>(EeW2, WBee2, 2, 16384);
  prep_bias4<<<2, 256, 0, stream>>>(MBih, MBhh, biasM);
  prep_bias4<<<2, 256, 0, stream>>>(UBih, UBhh, biasU);
  prep_gruWT_G<<<768, 256, 0, stream>>>(GWih, GWhh, WT_G);
  prep_biasG<<<2, 256, 0, stream>>>(GBih, GBhh, biasG);

  // ---- encoders ----
  enc_mfma<0><<<512, 256, 0, stream>>>(xh, eh, WBen1, EnB1, WBen2, EnB2);
  enc_mfma<1><<<4096, 256, 0, stream>>>(xh, eh, WBee1, EeB1, WBee2, EeB2);

  // ---- k = 3 message-passing iterations ----
  for (int it = 0; it < 3; ++it) {
    gru_mfma<0><<<4096, 256, 0, stream>>>(xh, eh, WTe, biasM);
    gru_mfma<1><<<512, 256, 0, stream>>>(xh, eh, WTu, biasU);
  }

  // ---- global readout ----
  sums2<<<2048, 256, 0, stream>>>(xh, eh, hsum, esum);
  gru_global<<<256, 256, 0, stream>>>(hsum, esum, g, WT_G, biasG);
  out_kernel<<<1024, 256, 0, stream>>>(g, OW, Ob, (float*)d_out);
}